// Round 12
// baseline (211.030 us; speedup 1.0000x reference)
//
#include <hip/hip_runtime.h>
#include <hip/hip_bf16.h>

// VectorQuantizer on MI355X — R19:
//  (a) vq_assign: conflict-free fragment path. The [row][72-short] LDS layout
//      put lane (col,quad) at bank 4*(col+quad)%32 -> 8-way conflict on every
//      ds_read_b128 (SQ_LDS_BANK_CONFLICT=2.1M, constant since R7, sitting on
//      the MFMA dep chain). vq_prep now packs per-lane MFMA fragments
//      pk[group][half][lane] (16B units); staging is a linear uint4 copy
//      (lane-linear ds_write_b128) and compute reads pkb[t*128+lane] — the
//      canonical lane*16B conflict-free pattern. Also kills per-block bf16
//      re-conversion VALU.
//  (b) 16 tok/wave, 128 tok/block -> 1024 blocks = 8192 waves; LDS 20.5KB ->
//      4 blocks/CU -> up to 32 waves/CU (grid was the occupancy cap at 16).
//      No launch_bounds min-wave hint (R14: forced VGPR=32 -> spill disaster).
//  (c) tail (fused dwred + final, nchunks=64) unchanged from R18.
// Inputs (fp32): z[NT,64], codebook[K,64], cluster_size[K], ema_w[K,64]
// d_out (fp32): quantized[NT*64] | indices[NT] | loss[1] | new_codebook[K*64] |
//   new_cluster_size[K] | new_ema_w[K*64]
// ws dwords: cnt[K](int) | cnormp[K] | loss | n | pad | pk[ngrp*512] |
//   partial[nchunks][K*64]

#define DECAY 0.99f
#define OMD   0.01f
#define EPSV  1e-5f
#define BIASF 192.0f    // folded into MFMA acc init: score' = 192 + z.c - |c|^2/2 > 0
#define KCH   128       // codes per staged chunk (8 groups x 2KB = 16KB LDS)

typedef __attribute__((ext_vector_type(8))) __bf16 bf16x8;
typedef __attribute__((ext_vector_type(4))) float  float4v;
typedef __attribute__((ext_vector_type(4))) unsigned int uint4v;

static __device__ __forceinline__ bf16x8 cvt8(float4v a, float4v b) {
    bf16x8 r;
    r[0] = (__bf16)a[0]; r[1] = (__bf16)a[1]; r[2] = (__bf16)a[2]; r[3] = (__bf16)a[3];
    r[4] = (__bf16)b[0]; r[5] = (__bf16)b[1]; r[6] = (__bf16)b[2]; r[7] = (__bf16)b[3];
    return r;
}

// key low 8 bits: iter = (global_group<<2)|r ; code = grp*16 + quad*4 + r
static __device__ __forceinline__ int dec_idx(unsigned key, int quad) {
    int iter = key & 255;
    return ((iter >> 2) << 4) + (quad << 2) + (iter & 3);
}

// Grid covers ngrp*64 threads (one per (group, lane) fragment pair) + K cnorm.
__global__ void vq_prep(const float* __restrict__ cb,
                        float* __restrict__ wsf, int* __restrict__ wsi,
                        uint4v* __restrict__ pk,
                        int K, int NT) {
    const int ngrp = (K + 15) >> 4;
    int t = blockIdx.x * 256 + threadIdx.x;
    if (t < K) {
        wsi[t] = 0;                               // cnt
        const float4v* cp = (const float4v*)(cb + (size_t)t * 64);
        float s = 0.f;
        #pragma unroll
        for (int i = 0; i < 16; ++i) {
            float4v v = cp[i];
            s += v[0] * v[0] + v[1] * v[1] + v[2] * v[2] + v[3] * v[3];
        }
        wsf[K + t] = BIASF - 0.5f * s;            // cnormp
    }
    if (t < ngrp * 64) {                          // fragment packing
        int tg  = t >> 6;                         // 16-code group
        int l   = t & 63;                         // lane
        int col = l & 15, q = l >> 4;
        int code = tg * 16 + col;
        bf16x8 a0, a1;
        if (code < K) {
            const float* s0 = cb + (size_t)code * 64 + q * 8;
            a0 = cvt8(*(const float4v*)(s0),      *(const float4v*)(s0 + 4));
            a1 = cvt8(*(const float4v*)(s0 + 32), *(const float4v*)(s0 + 36));
        } else {
            #pragma unroll
            for (int j = 0; j < 8; ++j) { a0[j] = (__bf16)0.f; a1[j] = (__bf16)0.f; }
        }
        pk[(size_t)tg * 128 + l]      = __builtin_bit_cast(uint4v, a0);
        pk[(size_t)tg * 128 + 64 + l] = __builtin_bit_cast(uint4v, a1);
    }
    if (t == 0) wsf[2 * K] = 0.f;                 // loss
}

// 512 threads = 8 waves; 128 tokens/block (16/wave); 1024 blocks.
// Per chunk: linear uint4 stage of 8 pre-packed fragment groups (16KB),
// then conflict-free lane*16B ds_read_b128 + MFMA + top-2 key updates.
__launch_bounds__(512)
__global__ void vq_assign(const float* __restrict__ z,
                          const float* __restrict__ cb,
                          const uint4v* __restrict__ pk,
                          float* __restrict__ wsf, int* __restrict__ wsi,
                          float* __restrict__ out,
                          int NT, int K) {
    __shared__ __align__(16) uint4v pkb[1024];    // 16 KB: 8 grp x [2][64]
    __shared__ float cns[KCH];
    __shared__ int hist[1024];

    const int tid  = threadIdx.x;
    const int lane = tid & 63;
    const int wave = tid >> 6;
    const int col  = lane & 15;
    const int quad = lane >> 4;
    const int wtok0 = blockIdx.x * 128 + wave * 16;
    const float* cnormp = wsf + K;
    const bool smallK = (K <= 1024);

    for (int i = tid; i < 1024; i += 512) hist[i] = 0;

    bf16x8 bf0, bf1;
    {
        int tok = wtok0 + col;
        if (tok >= NT) tok = NT - 1;
        const float* zp = z + (size_t)tok * 64 + quad * 8;
        bf0 = cvt8(*(const float4v*)(zp),      *(const float4v*)(zp + 4));
        bf1 = cvt8(*(const float4v*)(zp + 32), *(const float4v*)(zp + 36));
    }

    unsigned k1 = 0u, k2 = 0u;
    const unsigned kmask = 0xFFFFFF00u;
    const int ngrp  = (K + 15) >> 4;
    const int nch   = (ngrp + 7) >> 3;
    const int pktot = ngrp * 128;                 // uint4 count

    for (int c = 0; c < nch; ++c) {
        #pragma unroll
        for (int i = 0; i < 2; ++i) {             // 16KB / 512thr = 2 uint4/thr
            int idx = c * 1024 + i * 512 + tid;
            uint4v v = { 0u, 0u, 0u, 0u };
            if (idx < pktot) v = pk[idx];
            pkb[i * 512 + tid] = v;               // lane-linear ds_write_b128
        }
        if (tid < KCH) {
            int code = c * KCH + tid;
            cns[tid] = (code < K) ? cnormp[code] : 0.0f;
        }
        __syncthreads();

        #pragma unroll
        for (int t = 0; t < 8; ++t) {
            const int gg = c * 8 + t;
            if (gg < ngrp) {
                bf16x8 a0 = __builtin_bit_cast(bf16x8, pkb[t * 128 + lane]);
                bf16x8 a1 = __builtin_bit_cast(bf16x8, pkb[t * 128 + 64 + lane]);
                float4v acc = *(const float4v*)(cns + t * 16 + quad * 4);
                acc = __builtin_amdgcn_mfma_f32_16x16x32_bf16(a0, bf0, acc, 0, 0, 0);
                acc = __builtin_amdgcn_mfma_f32_16x16x32_bf16(a1, bf1, acc, 0, 0, 0);
                const int iterbase = gg << 2;
                #pragma unroll
                for (int r = 0; r < 4; ++r) {
                    unsigned kb = (__float_as_uint(acc[r]) & kmask) | (unsigned)(iterbase + r);
                    unsigned lo = k2 > kb ? k2 : kb;
                    k2 = k1 < lo ? k1 : lo;
                    k1 = k1 > kb ? k1 : kb;
                }
            }
        }
        __syncthreads();
    }

    // Cooperative exact refine: 4 quad-lanes per token jointly rerank the
    // token's 8 candidates in fp64; each lane covers a 16-dim slice.
    int ibst;
    {
        int tok = wtok0 + col;
        if (tok >= NT) tok = NT - 1;
        int ia = dec_idx(k1, quad);
        int ib = dec_idx(k2, quad);
        int cand[8];
        #pragma unroll
        for (int q = 0; q < 4; ++q) {
            cand[2 * q]     = __shfl(ia, q * 16 + col, 64);
            cand[2 * q + 1] = __shfl(ib, q * 16 + col, 64);
        }
        const float* zr = z + (size_t)tok * 64 + quad * 16;
        float4v zv0 = *(const float4v*)(zr);
        float4v zv1 = *(const float4v*)(zr + 4);
        float4v zv2 = *(const float4v*)(zr + 8);
        float4v zv3 = *(const float4v*)(zr + 12);
        double ps[8];
        #pragma unroll
        for (int s = 0; s < 8; ++s) {
            int cc = (cand[s] < K) ? cand[s] : 0;
            const float* cr = cb + (size_t)cc * 64 + quad * 16;
            float4v c0 = *(const float4v*)(cr);
            float4v c1 = *(const float4v*)(cr + 4);
            float4v c2 = *(const float4v*)(cr + 8);
            float4v c3 = *(const float4v*)(cr + 12);
            double a = 0.0;
            #pragma unroll
            for (int j = 0; j < 4; ++j) {
                double e0 = (double)zv0[j] - (double)c0[j];
                double e1 = (double)zv1[j] - (double)c1[j];
                double e2 = (double)zv2[j] - (double)c2[j];
                double e3 = (double)zv3[j] - (double)c3[j];
                a = fma(e0, e0, a); a = fma(e1, e1, a);
                a = fma(e2, e2, a); a = fma(e3, e3, a);
            }
            ps[s] = (cand[s] < K) ? a : 1.0e300;
        }
        #pragma unroll
        for (int s = 0; s < 8; ++s) {
            ps[s] += __shfl_xor(ps[s], 16, 64);
            ps[s] += __shfl_xor(ps[s], 32, 64);
        }
        double bs = ps[0]; int bi = cand[0];
        #pragma unroll
        for (int s = 1; s < 8; ++s) {
            if (ps[s] < bs || (ps[s] == bs && cand[s] < bi)) { bs = ps[s]; bi = cand[s]; }
        }
        ibst = bi;
    }

    const size_t off_idx = (size_t)NT * 64;

    if (lane < 16) {
        int tk = wtok0 + lane;
        if (tk < NT) {
            out[off_idx + tk] = (float)ibst;      // lane==col: own token
            if (smallK) atomicAdd(&hist[ibst], 1);
            else        atomicAdd(&wsi[ibst], 1);
        }
    }

    __syncthreads();
    if (smallK) {
        for (int k = tid; k < K; k += 512) {
            int c = hist[k];
            if (c) atomicAdd(&wsi[k], c);
        }
    }
}

// Dimension-partitioned dw scatter + FUSED quantized write / commitment loss
// (R18, unchanged). Block (chunk, g) owns dims [g*16,+16) of ALL K codes in
// 64KB LDS and token range [chunk*C, +C). Exclusive partial writeout; one
// loss atomic per block. Block 0 folds the nsum duty.
__launch_bounds__(512)
__global__ void vq_dwred(const float* __restrict__ z,
                         const float* __restrict__ cb,
                         const float* __restrict__ out_idx,
                         const float* __restrict__ cs,
                         float* __restrict__ wsf, const int* __restrict__ wsi,
                         float* __restrict__ partial,
                         float* __restrict__ out,
                         int NT, int K, int nchunks) {
    extern __shared__ float acc[];               // K*16 floats
    __shared__ float red[8];

    const int tid   = threadIdx.x;
    const int lane  = tid & 63;
    const int wave  = tid >> 6;                  // 8 waves
    const int chunk = blockIdx.x >> 2;
    const int g     = blockIdx.x & 3;
    const int tsub  = lane >> 4;
    const int d     = lane & 15;
    const size_t KD = (size_t)K * 64;

    for (int i = tid; i < K * 16; i += 512) acc[i] = 0.f;

    if (blockIdx.x == 0) {
        // folded nsum duty (cnt ready: vq_assign completed before this kernel)
        float part = 0.f;
        for (int k = tid; k < K; k += 512)
            part += DECAY * cs[k] + OMD * (float)wsi[k];
        #pragma unroll
        for (int off = 1; off < 64; off <<= 1) part += __shfl_xor(part, off, 64);
        if (lane == 0) red[wave] = part;
        __syncthreads();
        if (tid == 0) {
            float nn = 0.f;
            #pragma unroll
            for (int i = 0; i < 8; ++i) nn += red[i];
            wsf[2 * K + 1] = nn;                                  // n
        }
    }
    __syncthreads();

    const int C  = (NT + nchunks - 1) / nchunks;
    const int T0 = chunk * C;
    const int T1 = (T0 + C < NT) ? (T0 + C) : NT;
    const int doff = g * 16 + d;
    const float* zs = z + doff;

    float lsum = 0.f;
    #pragma unroll 4
    for (int t = T0 + wave * 4 + tsub; t < T1; t += 32) {
        float v   = zs[(size_t)t * 64];
        int  code = (int)out_idx[t];
        float q   = cb[(size_t)code * 64 + doff];
        out[(size_t)t * 64 + doff] = q;
        float e = v - q;
        lsum += e * e;
        atomicAdd(&acc[code * 16 + d], v);
    }
    #pragma unroll
    for (int off = 1; off < 64; off <<= 1) lsum += __shfl_xor(lsum, off, 64);
    __syncthreads();                              // acc complete; red reusable
    if (lane == 0) red[wave] = lsum;
    __syncthreads();
    if (tid == 0) {
        float s = 0.f;
        #pragma unroll
        for (int i = 0; i < 8; ++i) s += red[i];
        atomicAdd(&wsf[2 * K], s);                // loss accumulator
    }

    // exclusive writeout: dims [g*16, g*16+16) of partial[chunk]
    float* pb = partial + (size_t)chunk * KD + g * 16;
    for (int i = tid; i < K * 16; i += 512) {
        int k = i >> 4, dd = i & 15;
        pb[(size_t)k * 64 + dd] = acc[i];
    }
}

// Final: sum chunk partials -> new_ema_w, new_codebook, new_cluster_size.
// 8 independent accumulators -> 8 outstanding loads. Normalizes loss.
__global__ void vq_final(const float* __restrict__ cs,
                         const float* __restrict__ ema,
                         const float* __restrict__ wsf,
                         const int* __restrict__ wsi,
                         const float* __restrict__ partial,
                         float* __restrict__ out, int NT, int K, int S) {
    const int KD = K * 64;
    int t = blockIdx.x * 256 + threadIdx.x;
    if (t == 0) out[(size_t)NT * 64 + NT] = wsf[2 * K] / ((float)NT * 64.0f);
    if (t >= KD) return;
    const int k = t >> 6;
    const float n = wsf[2 * K + 1];
    float d0 = 0.f, d1 = 0.f, d2 = 0.f, d3 = 0.f;
    float d4 = 0.f, d5 = 0.f, d6 = 0.f, d7 = 0.f;
    int s = 0;
    for (; s + 8 <= S; s += 8) {
        d0 += partial[(size_t)(s + 0) * KD + t];
        d1 += partial[(size_t)(s + 1) * KD + t];
        d2 += partial[(size_t)(s + 2) * KD + t];
        d3 += partial[(size_t)(s + 3) * KD + t];
        d4 += partial[(size_t)(s + 4) * KD + t];
        d5 += partial[(size_t)(s + 5) * KD + t];
        d6 += partial[(size_t)(s + 6) * KD + t];
        d7 += partial[(size_t)(s + 7) * KD + t];
    }
    for (; s < S; ++s) d0 += partial[(size_t)s * KD + t];
    const float dsum = ((d0 + d1) + (d2 + d3)) + ((d4 + d5) + (d6 + d7));
    const float dw = DECAY * ema[t] + OMD * dsum;
    const float ncs = DECAY * cs[k] + OMD * (float)wsi[k];
    const float csn = (ncs + EPSV) / (n + (float)K * EPSV) * n;
    const size_t off_cb  = (size_t)NT * 64 + NT + 1;
    const size_t off_cs  = off_cb + (size_t)KD;
    const size_t off_ema = off_cs + K;
    out[off_cb  + t] = dw / csn;
    out[off_ema + t] = dw;
    if ((t & 63) == 0) out[off_cs + k] = ncs;
}

extern "C" void kernel_launch(void* const* d_in, const int* in_sizes, int n_in,
                              void* d_out, int out_size, void* d_ws, size_t ws_size,
                              hipStream_t stream) {
    const float* z   = (const float*)d_in[0];
    const float* cb  = (const float*)d_in[1];
    const float* cs  = (const float*)d_in[2];
    const float* ema = (const float*)d_in[3];
    float* out = (float*)d_out;
    float* wsf = (float*)d_ws;
    int*   wsi = (int*)d_ws;

    const int NT = in_sizes[0] / 64;
    const int K  = in_sizes[2];
    const int KD = K * 64;
    const int ngrp = (K + 15) >> 4;

    // ws layout (dwords): [0,K) cnt | [K,2K) cnormp | 2K loss | 2K+1 n |
    //   off_pk: pk (ngrp*512 dwords, 16B-aligned) | off_pa: partials
    const size_t off_pk = (((size_t)2 * K + 2) + 7) & ~(size_t)7;
    const size_t off_pa = off_pk + (size_t)ngrp * 512;

    size_t avail = ws_size / 4;                  // dwords
    int nchunks = 64;
    while (nchunks > 1 && off_pa + (size_t)nchunks * KD > avail)
        nchunks >>= 1;

    uint4v* pk = (uint4v*)(wsf + off_pk);
    float* partial = wsf + off_pa;
    const size_t dwlds = (size_t)K * 16 * sizeof(float);   // 64KB @ K=1024

    vq_prep<<<(ngrp * 64 + 255) / 256, 256, 0, stream>>>(cb, wsf, wsi, pk, K, NT);
    vq_assign<<<(NT + 127) / 128, 512, 0, stream>>>(z, cb, pk, wsf, wsi, out, NT, K);
    vq_dwred<<<nchunks * 4, 512, dwlds, stream>>>(
        z, cb, out + (size_t)NT * 64, cs, wsf, wsi, partial, out, NT, K, nchunks);
    vq_final<<<(KD + 255) / 256, 256, 0, stream>>>(cs, ema, wsf, wsi, partial,
                                                   out, NT, K, nchunks);
}